// Round 2
// baseline (1990.096 us; speedup 1.0000x reference)
//
#include <hip/hip_runtime.h>
#include <hip/hip_bf16.h>
#include <stdint.h>

#define TSTEPS 4

// ---------------------------------------------------------------------------
// Stage 1: input LIF encoder (elementwise; reference's swapaxes cancel out).
// v <- v + (x - v)/2 ; s = (v >= 1) ; v <- s ? 0 : v   (same x every step)
// Arithmetic mirrors XLA rounding exactly (mul then add, no fma contraction).
// ---------------------------------------------------------------------------
__global__ void spike_encode_kernel(const float* __restrict__ x,
                                    __hip_bfloat16* __restrict__ s1,
                                    int n)
{
    int i = blockIdx.x * blockDim.x + threadIdx.x;
    if (i >= n) return;
    float xv = x[i];
    float v = 0.0f;
#pragma unroll
    for (int t = 0; t < TSTEPS; ++t) {
        v = __fadd_rn(v, __fmul_rn(__fsub_rn(xv, v), 0.5f));
        bool sp = (v >= 1.0f);
        s1[(size_t)t * n + i] = __float2bfloat16(sp ? 1.0f : 0.0f);
        v = sp ? 0.0f : v;
    }
}

// ---------------------------------------------------------------------------
// Fused GEMM (+bias) + multistep-LIF. A = spikes [T][M][K] (bf16, values 0/1),
// W = [K][N] fp32 row-major, bias = [N].
// For each 64x64 output tile: loop t=0..3, full K loop accumulating y_t,
// then LIF update with membrane v carried in registers across t.
// LAST=false: write spikes (bf16) to Sout[T][M][N].
// LAST=true : accumulate spike sum, write Out[M][N] = sum/4 (mean over T).
// 256 threads, 4x4 micro-tile per thread, BK=16 LDS staging.
// ---------------------------------------------------------------------------
template <int K, bool LAST>
__global__ __launch_bounds__(256)
void gemm_lif_kernel(const __hip_bfloat16* __restrict__ A,
                     const float* __restrict__ W,
                     const float* __restrict__ bias,
                     __hip_bfloat16* __restrict__ Sout,
                     float* __restrict__ Out,
                     int M, int N)
{
    constexpr int BM = 64, BN = 64, BK = 16;
    __shared__ float As[BK][BM];   // A tile, transposed: As[k][m]
    __shared__ float Ws[BK][BN];   // W tile: Ws[k][n]

    const int tid = threadIdx.x;
    const int tx = tid & 15;        // n-direction (16 threads)
    const int ty = tid >> 4;        // m-direction (16 threads)
    const int m0 = blockIdx.x * BM;
    const int n0 = blockIdx.y * BN;

    // A-tile load mapping: thread -> (row m0+a_m, 4 contiguous k at k0+a_k), 8B load
    const int a_m = tid >> 2;          // 0..63
    const int a_k = (tid & 3) << 2;    // 0,4,8,12
    // W-tile load mapping: thread -> (row k0+w_k, 4 contiguous n at n0+w_n), 16B load
    const int w_k = tid >> 4;          // 0..15
    const int w_n = (tid & 15) << 2;   // 0..60

    float vmem[4][4];                  // LIF membrane, persists across t
    float ssum[4][4];                  // spike sum (LAST only)
#pragma unroll
    for (int i = 0; i < 4; ++i)
#pragma unroll
        for (int j = 0; j < 4; ++j) { vmem[i][j] = 0.0f; ssum[i][j] = 0.0f; }

    float b4[4];
#pragma unroll
    for (int j = 0; j < 4; ++j) b4[j] = bias[n0 + tx * 4 + j];

    for (int t = 0; t < TSTEPS; ++t) {
        const __hip_bfloat16* At = A + (size_t)t * M * K;
        float acc[4][4];
#pragma unroll
        for (int i = 0; i < 4; ++i)
#pragma unroll
            for (int j = 0; j < 4; ++j) acc[i][j] = 0.0f;

        for (int k0 = 0; k0 < K; k0 += BK) {
            // global loads into registers
            uint2 araw = *reinterpret_cast<const uint2*>(
                At + (size_t)(m0 + a_m) * K + (k0 + a_k));
            float4 wv = *reinterpret_cast<const float4*>(
                W + (size_t)(k0 + w_k) * N + (n0 + w_n));

            // LDS writes (trailing __syncthreads of previous iter protects these)
            As[a_k + 0][a_m] = __uint_as_float(araw.x << 16);
            As[a_k + 1][a_m] = __uint_as_float(araw.x & 0xFFFF0000u);
            As[a_k + 2][a_m] = __uint_as_float(araw.y << 16);
            As[a_k + 3][a_m] = __uint_as_float(araw.y & 0xFFFF0000u);
            *reinterpret_cast<float4*>(&Ws[w_k][w_n]) = wv;
            __syncthreads();

#pragma unroll
            for (int k = 0; k < BK; ++k) {
                float4 av = *reinterpret_cast<const float4*>(&As[k][ty * 4]);
                float4 wv2 = *reinterpret_cast<const float4*>(&Ws[k][tx * 4]);
                float a[4] = {av.x, av.y, av.z, av.w};
                float w[4] = {wv2.x, wv2.y, wv2.z, wv2.w};
#pragma unroll
                for (int i = 0; i < 4; ++i)
#pragma unroll
                    for (int j = 0; j < 4; ++j)
                        acc[i][j] += a[i] * w[j];
            }
            __syncthreads();
        }

        // LIF epilogue for this timestep (XLA-exact rounding on the scan)
#pragma unroll
        for (int i = 0; i < 4; ++i) {
            uint32_t bits[4];
#pragma unroll
            for (int j = 0; j < 4; ++j) {
                float y = __fadd_rn(acc[i][j], b4[j]);
                float v = vmem[i][j];
                v = __fadd_rn(v, __fmul_rn(__fsub_rn(y, v), 0.5f));
                bool sp = (v >= 1.0f);
                vmem[i][j] = sp ? 0.0f : v;
                if (LAST) {
                    ssum[i][j] += sp ? 1.0f : 0.0f;
                } else {
                    bits[j] = sp ? 0x3F80u : 0u;  // bf16(1.0)/bf16(0.0)
                }
            }
            if (!LAST) {
                uint2 pack;
                pack.x = bits[0] | (bits[1] << 16);
                pack.y = bits[2] | (bits[3] << 16);
                size_t off = (size_t)t * M * N + (size_t)(m0 + ty * 4 + i) * N
                             + (n0 + tx * 4);
                *reinterpret_cast<uint2*>(Sout + off) = pack;
            }
        }
    }

    if (LAST) {
#pragma unroll
        for (int i = 0; i < 4; ++i) {
            float4 o;
            o.x = ssum[i][0] * 0.25f;
            o.y = ssum[i][1] * 0.25f;
            o.z = ssum[i][2] * 0.25f;
            o.w = ssum[i][3] * 0.25f;
            *reinterpret_cast<float4*>(
                Out + (size_t)(m0 + ty * 4 + i) * N + (n0 + tx * 4)) = o;
        }
    }
}

// ---------------------------------------------------------------------------
// out2[b][d] = mean over L of out[b][l][d]. Exact in fp32 (quarter-integers).
// Consecutive threads -> consecutive d -> coalesced.
// ---------------------------------------------------------------------------
__global__ void mean_over_L_kernel(const float* __restrict__ out,
                                   float* __restrict__ out2,
                                   int B, int L, int D)
{
    int id = blockIdx.x * blockDim.x + threadIdx.x;
    if (id >= B * D) return;
    int b = id / D, d = id - b * D;
    const float* p = out + (size_t)b * L * D + d;
    float s = 0.0f;
    for (int l = 0; l < L; ++l) s += p[(size_t)l * D];
    out2[id] = s * (1.0f / (float)L);
}

// ---------------------------------------------------------------------------
extern "C" void kernel_launch(void* const* d_in, const int* in_sizes, int n_in,
                              void* d_out, int out_size, void* d_ws, size_t ws_size,
                              hipStream_t stream)
{
    const float* inputs  = (const float*)d_in[0];  // [16,512,128]
    const float* enc_W   = (const float*)d_in[1];  // [128,1024]
    const float* enc_b   = (const float*)d_in[2];  // [1024]
    const float* W_cells = (const float*)d_in[3];  // [2,1024,1024]
    const float* b_cells = (const float*)d_in[4];  // [2,1024]

    const int B = 16, L = 512, C = 128, D = 1024;
    const int M = B * L;  // 8192

    // workspace layout (all bf16 spike buffers):
    //   s1: [T][M][C]  =  8 MiB
    //   h0: [T][M][D]  = 64 MiB
    //   h1: [T][M][D]  = 64 MiB
    char* ws = (char*)d_ws;
    __hip_bfloat16* s1 = (__hip_bfloat16*)ws;
    __hip_bfloat16* h0 = (__hip_bfloat16*)(ws + (size_t)TSTEPS * M * C * 2);
    __hip_bfloat16* h1 = (__hip_bfloat16*)(ws + (size_t)TSTEPS * M * C * 2
                                              + (size_t)TSTEPS * M * D * 2);

    float* out  = (float*)d_out;          // [M, D]
    float* out2 = out + (size_t)M * D;    // [B, D]

    const int n1 = M * C;
    spike_encode_kernel<<<(n1 + 255) / 256, 256, 0, stream>>>(inputs, s1, n1);

    dim3 grid(M / 64, D / 64);
    gemm_lif_kernel<128, false><<<grid, 256, 0, stream>>>(
        s1, enc_W, enc_b, h0, nullptr, M, D);
    gemm_lif_kernel<1024, false><<<grid, 256, 0, stream>>>(
        h0, W_cells, b_cells, h1, nullptr, M, D);
    gemm_lif_kernel<1024, true><<<grid, 256, 0, stream>>>(
        h1, W_cells + (size_t)D * D, b_cells + D, nullptr, out, M, D);

    mean_over_L_kernel<<<(B * D + 255) / 256, 256, 0, stream>>>(
        out, out2, B, L, D);
}

// Round 3
// 506.435 us; speedup vs baseline: 3.9296x; 3.9296x over previous
//
#include <hip/hip_runtime.h>
#include <hip/hip_bf16.h>
#include <stdint.h>

#define TSTEPS 4

typedef __bf16 bf16_t;
typedef __attribute__((ext_vector_type(8))) __bf16 bf16x8;
typedef __attribute__((ext_vector_type(4))) float f32x4;

typedef const __attribute__((address_space(1))) void* gas_ptr;
typedef __attribute__((address_space(3))) void* las_ptr;

__device__ __forceinline__ void glds16(const void* g, void* l) {
    // 16B per lane, LDS dest = wave-uniform base + lane*16
    __builtin_amdgcn_global_load_lds((gas_ptr)g, (las_ptr)l, 16, 0, 0);
}

// ---------------------------------------------------------------------------
// Stage 1: input LIF encoder (elementwise). XLA-exact rounding.
// ---------------------------------------------------------------------------
__global__ void spike_encode_kernel(const float* __restrict__ x,
                                    unsigned short* __restrict__ s1, int n)
{
    int i = blockIdx.x * blockDim.x + threadIdx.x;
    if (i >= n) return;
    float xv = x[i];
    float v = 0.0f;
#pragma unroll
    for (int t = 0; t < TSTEPS; ++t) {
        v = __fadd_rn(v, __fmul_rn(__fsub_rn(xv, v), 0.5f));
        bool sp = (v >= 1.0f);
        s1[(size_t)t * n + i] = sp ? 0x3F80 : 0;   // bf16 1.0 / 0.0
        v = sp ? 0.0f : v;
    }
}

// ---------------------------------------------------------------------------
// Weight prep: W [K][N] fp32 -> hiT, loT [N][K] bf16 (2-term split, transposed
// so B-fragments read contiguous k). Tiled transpose via LDS.
// ---------------------------------------------------------------------------
__global__ void split_transpose_kernel(const float* __restrict__ W,
                                       bf16_t* __restrict__ hiT,
                                       bf16_t* __restrict__ loT,
                                       int K, int N)
{
    __shared__ float tile[32][33];
    int k0 = blockIdx.x * 32, n0 = blockIdx.y * 32;
    int tx = threadIdx.x & 31, ty = threadIdx.x >> 5;  // 8 rows per pass
    for (int kk = ty; kk < 32; kk += 8)
        tile[kk][tx] = W[(size_t)(k0 + kk) * N + n0 + tx];
    __syncthreads();
    for (int nn = ty; nn < 32; nn += 8) {
        float w = tile[tx][nn];                 // = W[k0+tx][n0+nn]
        bf16_t h = (bf16_t)w;
        bf16_t l = (bf16_t)(w - (float)h);
        size_t o = (size_t)(n0 + nn) * K + (k0 + tx);
        hiT[o] = h;
        loT[o] = l;
    }
}

// ---------------------------------------------------------------------------
// Fused MFMA GEMM + multistep LIF.
// A: spikes [T][M][K] bf16 (0/1 exact). WhiT/WloT: [N][K] bf16 split weights.
// Block: 128x128 tile, 4 waves of 64x64, mfma_f32_16x16x32_bf16, 2 MFMAs
// (hi+lo) chained into the same fp32 accumulator per (tile, k-slab).
// t-outer loop; membrane v carried in registers across t.
// LAST=false: write spikes bf16 to Sout[T][M][N].
// LAST=true : pack spike bits, write Out[M][N] = popcount/4.
//
// LDS swizzle: 16B chunk at slot s of row r holds global k-quad
// kq = (s - r - (r>>2)) & 3, so frag reads (row=..+il, slot=(q+row+row>>2)&3)
// land exactly 2 lanes per bank group = conflict-free (m136: 2-way is free),
// while the LDS destination stays lane-linear for global_load_lds.
// ---------------------------------------------------------------------------
template <int K, bool LAST>
__global__ __launch_bounds__(256, 2)
void gemm_lif_mfma(const unsigned short* __restrict__ A,
                   const bf16_t* __restrict__ WhiT,
                   const bf16_t* __restrict__ WloT,
                   const float* __restrict__ bias,
                   unsigned short* __restrict__ Sout,
                   float* __restrict__ Out,
                   int M, int N)
{
    constexpr int BK = 32;
    __shared__ bf16_t As[128 * BK];   // 8 KB
    __shared__ bf16_t Bh[128 * BK];   // 8 KB
    __shared__ bf16_t Bl[128 * BK];   // 8 KB

    const int tid = threadIdx.x;
    const int lane = tid & 63;
    const int wid = tid >> 6;
    const int il = lane & 15;
    const int q = lane >> 4;
    const int wave_m = (wid & 1) * 64;
    const int wave_n = (wid >> 1) * 64;
    const int m0 = blockIdx.x * 128;
    const int n0 = blockIdx.y * 128;

    // --- staging descriptors: 512 chunks of 16B per tile, 2 rounds/thread ---
    const int i0 = wid * 64 + lane;
    const int i1 = i0 + 256;
    const int r0 = i0 >> 2, r1 = i1 >> 2;
    const int kq0 = ((i0 & 3) - r0 - (r0 >> 2)) & 3;
    const int kq1 = ((i1 & 3) - r1 - (r1 >> 2)) & 3;

    bf16_t* ldsA0 = As + (wid * 64) * 8;          // +lane*16B implicit
    bf16_t* ldsA1 = As + (256 + wid * 64) * 8;
    bf16_t* ldsBh0 = Bh + (wid * 64) * 8;
    bf16_t* ldsBh1 = Bh + (256 + wid * 64) * 8;
    bf16_t* ldsBl0 = Bl + (wid * 64) * 8;
    bf16_t* ldsBl1 = Bl + (256 + wid * 64) * 8;

    const size_t rowBytesA0 = (size_t)(m0 + r0) * K * 2 + (size_t)kq0 * 16;
    const size_t rowBytesA1 = (size_t)(m0 + r1) * K * 2 + (size_t)kq1 * 16;
    const char* pBh0 = (const char*)WhiT + (size_t)(n0 + r0) * K * 2 + kq0 * 16;
    const char* pBh1 = (const char*)WhiT + (size_t)(n0 + r1) * K * 2 + kq1 * 16;
    const char* pBl0 = (const char*)WloT + (size_t)(n0 + r0) * K * 2 + kq0 * 16;
    const char* pBl1 = (const char*)WloT + (size_t)(n0 + r1) * K * 2 + kq1 * 16;

    // --- fragment LDS byte offsets (constant, single-buffered) ---
    int offA[4], offB[4];
#pragma unroll
    for (int mt = 0; mt < 4; ++mt) {
        int row = wave_m + mt * 16 + il;
        int s = (q + row + (row >> 2)) & 3;
        offA[mt] = row * 64 + s * 16;
    }
#pragma unroll
    for (int nt = 0; nt < 4; ++nt) {
        int row = wave_n + nt * 16 + il;
        int s = (q + row + (row >> 2)) & 3;
        offB[nt] = row * 64 + s * 16;
    }

    float biasv[4];
#pragma unroll
    for (int nt = 0; nt < 4; ++nt)
        biasv[nt] = bias[n0 + wave_n + nt * 16 + il];

    f32x4 v[4][4];
    uint32_t bits[4][4];
#pragma unroll
    for (int mt = 0; mt < 4; ++mt)
#pragma unroll
        for (int nt = 0; nt < 4; ++nt) {
            v[mt][nt] = (f32x4){0.f, 0.f, 0.f, 0.f};
            bits[mt][nt] = 0u;
        }

    for (int t = 0; t < TSTEPS; ++t) {
        const char* At = (const char*)A + (size_t)t * M * K * 2;
        f32x4 acc[4][4];
#pragma unroll
        for (int mt = 0; mt < 4; ++mt)
#pragma unroll
            for (int nt = 0; nt < 4; ++nt)
                acc[mt][nt] = (f32x4){0.f, 0.f, 0.f, 0.f};

        for (int kk = 0; kk < K; kk += BK) {
            const size_t kb = (size_t)kk * 2;
            glds16(At + rowBytesA0 + kb, ldsA0);
            glds16(At + rowBytesA1 + kb, ldsA1);
            glds16(pBh0 + kb, ldsBh0);
            glds16(pBh1 + kb, ldsBh1);
            glds16(pBl0 + kb, ldsBl0);
            glds16(pBl1 + kb, ldsBl1);
            __syncthreads();   // drains vmcnt -> LDS tiles valid

            bf16x8 af[4], fh[4], fl[4];
#pragma unroll
            for (int mt = 0; mt < 4; ++mt)
                af[mt] = *(const bf16x8*)((const char*)As + offA[mt]);
#pragma unroll
            for (int nt = 0; nt < 4; ++nt) {
                fh[nt] = *(const bf16x8*)((const char*)Bh + offB[nt]);
                fl[nt] = *(const bf16x8*)((const char*)Bl + offB[nt]);
            }
#pragma unroll
            for (int mt = 0; mt < 4; ++mt)
#pragma unroll
                for (int nt = 0; nt < 4; ++nt) {
                    acc[mt][nt] = __builtin_amdgcn_mfma_f32_16x16x32_bf16(
                        af[mt], fh[nt], acc[mt][nt], 0, 0, 0);
                    acc[mt][nt] = __builtin_amdgcn_mfma_f32_16x16x32_bf16(
                        af[mt], fl[nt], acc[mt][nt], 0, 0, 0);
                }
            __syncthreads();   // reads done before next stage overwrites
        }

        // --- LIF epilogue for timestep t (XLA-exact scan arithmetic) ---
#pragma unroll
        for (int mt = 0; mt < 4; ++mt)
#pragma unroll
            for (int nt = 0; nt < 4; ++nt)
#pragma unroll
                for (int r = 0; r < 4; ++r) {
                    float y = __fadd_rn(acc[mt][nt][r], biasv[nt]);
                    float vv = v[mt][nt][r];
                    vv = __fadd_rn(vv, __fmul_rn(__fsub_rn(y, vv), 0.5f));
                    bool sp = (vv >= 1.0f);
                    v[mt][nt][r] = sp ? 0.0f : vv;
                    if (LAST) {
                        bits[mt][nt] |= sp ? (1u << (r * 4 + t)) : 0u;
                    } else {
                        int m = m0 + wave_m + mt * 16 + q * 4 + r;
                        int n = n0 + wave_n + nt * 16 + il;
                        Sout[(size_t)t * M * N + (size_t)m * N + n] =
                            sp ? 0x3F80 : 0;
                    }
                }
    }

    if (LAST) {
#pragma unroll
        for (int mt = 0; mt < 4; ++mt)
#pragma unroll
            for (int nt = 0; nt < 4; ++nt)
#pragma unroll
                for (int r = 0; r < 4; ++r) {
                    int m = m0 + wave_m + mt * 16 + q * 4 + r;
                    int n = n0 + wave_n + nt * 16 + il;
                    int cnt = __popc((bits[mt][nt] >> (r * 4)) & 0xF);
                    Out[(size_t)m * N + n] = 0.25f * (float)cnt;
                }
    }
}

// ---------------------------------------------------------------------------
// out2[b][d] = mean over L of out[b][l][d]. Exact in fp32 (quarter-integers).
// ---------------------------------------------------------------------------
__global__ void mean_over_L_kernel(const float* __restrict__ out,
                                   float* __restrict__ out2,
                                   int B, int L, int D)
{
    int id = blockIdx.x * blockDim.x + threadIdx.x;
    if (id >= B * D) return;
    int b = id / D, d = id - b * D;
    const float* p = out + (size_t)b * L * D + d;
    float s = 0.0f;
    for (int l = 0; l < L; ++l) s += p[(size_t)l * D];
    out2[id] = s * (1.0f / (float)L);
}

// ---------------------------------------------------------------------------
extern "C" void kernel_launch(void* const* d_in, const int* in_sizes, int n_in,
                              void* d_out, int out_size, void* d_ws, size_t ws_size,
                              hipStream_t stream)
{
    const float* inputs  = (const float*)d_in[0];  // [16,512,128]
    const float* enc_W   = (const float*)d_in[1];  // [128,1024]
    const float* enc_b   = (const float*)d_in[2];  // [1024]
    const float* W_cells = (const float*)d_in[3];  // [2,1024,1024]
    const float* b_cells = (const float*)d_in[4];  // [2,1024]

    const int B = 16, L = 512, C = 128, D = 1024;
    const int M = B * L;  // 8192

    // ws layout: s1 8MB | W1h/l 0.5MB | W2h/l 4MB | W3h/l 4MB | h0 64MB | h1 64MB
    char* ws = (char*)d_ws;
    size_t off = 0;
    unsigned short* s1 = (unsigned short*)(ws + off); off += (size_t)TSTEPS * M * C * 2;
    bf16_t* W1h = (bf16_t*)(ws + off); off += (size_t)C * D * 2;
    bf16_t* W1l = (bf16_t*)(ws + off); off += (size_t)C * D * 2;
    bf16_t* W2h = (bf16_t*)(ws + off); off += (size_t)D * D * 2;
    bf16_t* W2l = (bf16_t*)(ws + off); off += (size_t)D * D * 2;
    bf16_t* W3h = (bf16_t*)(ws + off); off += (size_t)D * D * 2;
    bf16_t* W3l = (bf16_t*)(ws + off); off += (size_t)D * D * 2;
    unsigned short* h0 = (unsigned short*)(ws + off); off += (size_t)TSTEPS * M * D * 2;
    unsigned short* h1 = (unsigned short*)(ws + off);

    float* out  = (float*)d_out;          // [M, D]
    float* out2 = out + (size_t)M * D;    // [B, D]

    split_transpose_kernel<<<dim3(C / 32, D / 32), 256, 0, stream>>>(
        enc_W, W1h, W1l, C, D);
    split_transpose_kernel<<<dim3(D / 32, D / 32), 256, 0, stream>>>(
        W_cells, W2h, W2l, D, D);
    split_transpose_kernel<<<dim3(D / 32, D / 32), 256, 0, stream>>>(
        W_cells + (size_t)D * D, W3h, W3l, D, D);

    const int n1 = M * C;
    spike_encode_kernel<<<(n1 + 255) / 256, 256, 0, stream>>>(inputs, s1, n1);

    dim3 grid(M / 128, D / 128);
    gemm_lif_mfma<128, false><<<grid, 256, 0, stream>>>(
        s1, W1h, W1l, enc_b, h0, nullptr, M, D);
    gemm_lif_mfma<1024, false><<<grid, 256, 0, stream>>>(
        h0, W2h, W2l, b_cells, h1, nullptr, M, D);
    gemm_lif_mfma<1024, true><<<grid, 256, 0, stream>>>(
        h1, W3h, W3l, b_cells + D, nullptr, out, M, D);

    mean_over_L_kernel<<<(B * D + 255) / 256, 256, 0, stream>>>(
        out, out2, B, L, D);
}